// Round 5
// baseline (37.615 us; speedup 1.0000x reference)
//
#include <hip/hip_runtime.h>

// BernsteinSplineCouplingBlock: BATCH=65536, CHANNELS=64, SPLIT1=SPLIT2=32, DEGREE=10
// out[:, :32] = x[:, :32]
// s = x1 @ W.T + b  -> [B*32, 12]; spline(s, x2) -> out[:, 32:]
// GEMM via split-bf16 (hi+lo) 3-MFMA chain for ~f32 precision.
// R5: channel-split x2 (2048 blocks, 16 ch/block) -> 20 waves/CU vs 16.
//     W-split precomputed to d_ws by prep kernel; deriv fused into main DC.

typedef short v8s  __attribute__((ext_vector_type(8)));  // 8 x bf16 (4 VGPRs)
typedef float f32x4 __attribute__((ext_vector_type(4)));

__device__ __forceinline__ short f2bf(float f) {
    union { float f; unsigned u; } v; v.f = f;
    return (short)((v.u + 0x7FFFu + ((v.u >> 16) & 1u)) >> 16);  // RNE
}

__device__ __forceinline__ float bf2f(short h) {
    union { unsigned u; float f; } v; v.u = ((unsigned)(unsigned short)h) << 16;
    return v.f;
}

__device__ __forceinline__ float softplus_f(float x) {
    return __logf(1.0f + __expf(x));   // s bounded (|s| < ~2): stable
}

__device__ __forceinline__ float sgn01(float x) {
    return (x > 0.f) ? 1.f : ((x < 0.f) ? -1.f : 0.f);
}

// sv[0..9]: coeff_raw, sv[10]: width raw, sv[11]: height raw. xf: x2 value.
__device__ __forceinline__ float spline_eval(const float* sv, float xf) {
    // cumsum(softplus) -> unnormalized coeffs [0, cs...]
    float cn[11];
    cn[0] = 0.f;
    float run = 0.f;
#pragma unroll
    for (int j = 0; j < 10; ++j) { run += softplus_f(sv[j]); cn[j + 1] = run; }
    const float inv = __fdividef(1.f, run);

    const float wd = softplus_f(sv[10]) + 0.1f;   // softplus>0 => sign==+1
    float hg = sv[11];
    hg += 0.1f * sgn01(hg);

    const float t   = __fdividef(xf, wd) + 0.5f;
    const float tc  = fminf(fmaxf(t, 0.f), 1.f);

    // de Casteljau, stop at degree 1 (9 steps): b0=cn[0], b1=cn[1]
#pragma unroll
    for (int n = 10; n >= 2; --n) {
#pragma unroll
        for (int i = 0; i < n; ++i) cn[i] += tc * (cn[i + 1] - cn[i]);
    }
    const float db    = cn[1] - cn[0];
    const float deriv = 10.f * db * inv;              // B'(t), normalized
    const float ym    = fmaf(tc, db, cn[0]) * inv;    // B(t),  normalized

    float y = (t < 0.f) ? (t * deriv)
            : ((t > 1.f) ? fmaf(t - 1.f, deriv, 1.f) : ym);
    return (y - 0.5f) * hg;
}

// ---- prep: split W f32 -> bf16 hi/lo in B-fragment order ----
// frag layout: [(k>>3)*3072 + out*8 + (k&7)], hi at wsH, lo at wsL
__global__ void prep_w(const float* __restrict__ W, short* __restrict__ wsH,
                       short* __restrict__ wsL) {
    const int g = blockIdx.x * 256 + threadIdx.x;
    if (g < 12288) {
        const int o = g >> 5;        // W row (out index 0..383)
        const int k = g & 31;
        const float w = W[g];
        const short hi = f2bf(w);
        const int off = (k >> 3) * 3072 + o * 8 + (k & 7);
        wsH[off] = hi;
        wsL[off] = f2bf(w - bf2f(hi));
    }
}

// ---- main: 2048 blocks = (row group 0..1023) x (channel half 0..1) ----
// 4 waves/block, 16 rows/wave, 16 channels/block, wave-private LDS, no barriers
__global__ __launch_bounds__(256) void bern_spline_fast(
    const float* __restrict__ x, const short* __restrict__ wsH,
    const short* __restrict__ wsL, const float* __restrict__ bias,
    float* __restrict__ out)
{
    __shared__ float sl[4 * 16 * 100];   // per-wave 16 rows x (96+4pad) f32, 25.6 KB

    const int tid  = threadIdx.x;
    const int wave = tid >> 6;
    const int lane = tid & 63;
    const int cbit = blockIdx.x & 1;            // channel half: ch in [cbit*16, +16)
    const int block_row = (blockIdx.x >> 1) * 64;

    // x1 passthrough: only even blocks (one copy per row group)
    if (cbit == 0) {
        for (int i = tid; i < 512; i += 256) {
            const int r = i >> 3, q = i & 7;               // 64 rows x 8 quads
            *(f32x4*)(out + (size_t)(block_row + r) * 64 + q * 4) =
                *(const f32x4*)(x + (size_t)(block_row + r) * 64 + q * 4);
        }
    }

    // A fragment: lane holds x1[row = l&15][k = (l>>4)*8 .. +7], hi+lo
    const int row16 = lane & 15;
    const int kq    = lane >> 4;
    const int arow  = block_row + wave * 16 + row16;
    const f32x4 a0 = *(const f32x4*)(x + (size_t)arow * 64 + kq * 8);
    const f32x4 a1 = *(const f32x4*)(x + (size_t)arow * 64 + kq * 8 + 4);
    v8s ah, al;
#pragma unroll
    for (int e = 0; e < 4; ++e) {
        const short h0 = f2bf(a0[e]);
        ah[e] = h0;     al[e] = f2bf(a0[e] - bf2f(h0));
        const short h1 = f2bf(a1[e]);
        ah[e + 4] = h1; al[e + 4] = f2bf(a1[e] - bf2f(h1));
    }

    float* swv = sl + wave * 1600;   // wave-private transpose buffer
    const f32x4 zero4 = {0.f, 0.f, 0.f, 0.f};

    for (int hf = 0; hf < 2; ++hf) {
        // GEMM half: 6 tiles x 3 MFMA (split-bf16), outs for 8 channels
        f32x4 acc[6];
#pragma unroll
        for (int ot = 0; ot < 6; ++ot) {
            const int otg  = cbit * 12 + hf * 6 + ot;
            const int boff = kq * 3072 + (otg * 16 + row16) * 8;
            const v8s bh  = *(const v8s*)(wsH + boff);   // global, L2-hot
            const v8s blo = *(const v8s*)(wsL + boff);
            f32x4 c = __builtin_amdgcn_mfma_f32_16x16x32_bf16(al, bh, zero4, 0, 0, 0);
            c = __builtin_amdgcn_mfma_f32_16x16x32_bf16(ah, blo, c, 0, 0, 0);
            acc[ot] = __builtin_amdgcn_mfma_f32_16x16x32_bf16(ah, bh, c, 0, 0, 0);
        }
        // C/D: row = (lane>>4)*4 + reg, col(out) = lane&15 -> scatter to LDS
#pragma unroll
        for (int ot = 0; ot < 6; ++ot)
#pragma unroll
            for (int r = 0; r < 4; ++r)
                swv[(kq * 4 + r) * 100 + ot * 16 + row16] = acc[ot][r];
        // wave-private region; same-wave DS ordering via compiler lgkmcnt

        // spline: 16 rows x 8 channels = 128 pairs, 2 per lane
#pragma unroll
        for (int p = 0; p < 2; ++p) {
            const int idx = p * 64 + lane;
            const int cl  = idx & 7;                  // local channel 0..7
            const int rr  = idx >> 3;                 // row 0..15
            const int cg  = cbit * 16 + hf * 8 + cl;  // global channel 0..31

            const float* sp = swv + rr * 100 + cl * 12;
            const f32x4 s0 = *(const f32x4*)(sp);
            const f32x4 s1 = *(const f32x4*)(sp + 4);
            const f32x4 s2 = *(const f32x4*)(sp + 8);
            const f32x4 b0 = *(const f32x4*)(bias + cg * 12);      // L1/L2-hot
            const f32x4 b1 = *(const f32x4*)(bias + cg * 12 + 4);
            const f32x4 b2 = *(const f32x4*)(bias + cg * 12 + 8);

            float sv[12];
            sv[0]  = s0[0] + b0[0]; sv[1]  = s0[1] + b0[1];
            sv[2]  = s0[2] + b0[2]; sv[3]  = s0[3] + b0[3];
            sv[4]  = s1[0] + b1[0]; sv[5]  = s1[1] + b1[1];
            sv[6]  = s1[2] + b1[2]; sv[7]  = s1[3] + b1[3];
            sv[8]  = s2[0] + b2[0]; sv[9]  = s2[1] + b2[1];
            sv[10] = s2[2] + b2[2]; sv[11] = s2[3] + b2[3];

            const int rowg = block_row + wave * 16 + rr;
            const float xf = x[(size_t)rowg * 64 + 32 + cg];
            out[(size_t)rowg * 64 + 32 + cg] = spline_eval(sv, xf);
        }
    }
}

// ---- fallback (R3 structure, known-pass): used only if ws is too small ----
__global__ __launch_bounds__(256) void bern_spline_fallback(
    const float* __restrict__ x, const float* __restrict__ W,
    const float* __restrict__ bias, float* __restrict__ out)
{
    __shared__ short Wh[12288];
    __shared__ short Wl[12288];
    __shared__ float bl[384];
    __shared__ float sl[4 * 16 * 100];

    const int tid  = threadIdx.x;
    const int wave = tid >> 6;
    const int lane = tid & 63;
    const int block_row = blockIdx.x * 64;

    for (int g = tid; g < 12288; g += 256) {
        const int o = g >> 5;
        const int k = g & 31;
        const float w = W[g];
        const short hi = f2bf(w);
        Wh[(k >> 3) * 3072 + o * 8 + (k & 7)] = hi;
        Wl[(k >> 3) * 3072 + o * 8 + (k & 7)] = f2bf(w - bf2f(hi));
    }
    for (int g = tid; g < 384; g += 256) bl[g] = bias[g];
    __syncthreads();

    for (int i = tid; i < 512; i += 256) {
        const int r = i >> 3, q = i & 7;
        *(f32x4*)(out + (size_t)(block_row + r) * 64 + q * 4) =
            *(const f32x4*)(x + (size_t)(block_row + r) * 64 + q * 4);
    }

    const int row16 = lane & 15;
    const int kq    = lane >> 4;
    const int arow  = block_row + wave * 16 + row16;
    const f32x4 a0 = *(const f32x4*)(x + (size_t)arow * 64 + kq * 8);
    const f32x4 a1 = *(const f32x4*)(x + (size_t)arow * 64 + kq * 8 + 4);
    v8s ah, al;
#pragma unroll
    for (int e = 0; e < 4; ++e) {
        const short h0 = f2bf(a0[e]);
        ah[e] = h0;     al[e] = f2bf(a0[e] - bf2f(h0));
        const short h1 = f2bf(a1[e]);
        ah[e + 4] = h1; al[e + 4] = f2bf(a1[e] - bf2f(h1));
    }

    float* swv = sl + wave * 1600;
    const f32x4 zero4 = {0.f, 0.f, 0.f, 0.f};

    for (int qt = 0; qt < 4; ++qt) {
        f32x4 acc[6];
#pragma unroll
        for (int ot = 0; ot < 6; ++ot) {
            const int otg = qt * 6 + ot;
            const int boff = kq * 3072 + (otg * 16 + row16) * 8;
            const v8s bh  = *(const v8s*)(Wh + boff);
            const v8s blo = *(const v8s*)(Wl + boff);
            f32x4 c = __builtin_amdgcn_mfma_f32_16x16x32_bf16(al, bh, zero4, 0, 0, 0);
            c = __builtin_amdgcn_mfma_f32_16x16x32_bf16(ah, blo, c, 0, 0, 0);
            acc[ot] = __builtin_amdgcn_mfma_f32_16x16x32_bf16(ah, bh, c, 0, 0, 0);
        }
#pragma unroll
        for (int ot = 0; ot < 6; ++ot)
#pragma unroll
            for (int r = 0; r < 4; ++r)
                swv[(kq * 4 + r) * 100 + ot * 16 + row16] = acc[ot][r];

#pragma unroll
        for (int p = 0; p < 2; ++p) {
            const int idx = p * 64 + lane;
            const int cl  = idx & 7;
            const int rr  = idx >> 3;
            const int cg  = qt * 8 + cl;

            const float* sp = swv + rr * 100 + cl * 12;
            const f32x4 s0 = *(const f32x4*)(sp);
            const f32x4 s1 = *(const f32x4*)(sp + 4);
            const f32x4 s2 = *(const f32x4*)(sp + 8);
            const f32x4 b0 = *(const f32x4*)(bl + cg * 12);
            const f32x4 b1 = *(const f32x4*)(bl + cg * 12 + 4);
            const f32x4 b2 = *(const f32x4*)(bl + cg * 12 + 8);

            float sv[12];
            sv[0]  = s0[0] + b0[0]; sv[1]  = s0[1] + b0[1];
            sv[2]  = s0[2] + b0[2]; sv[3]  = s0[3] + b0[3];
            sv[4]  = s1[0] + b1[0]; sv[5]  = s1[1] + b1[1];
            sv[6]  = s1[2] + b1[2]; sv[7]  = s1[3] + b1[3];
            sv[8]  = s2[0] + b2[0]; sv[9]  = s2[1] + b2[1];
            sv[10] = s2[2] + b2[2]; sv[11] = s2[3] + b2[3];

            const int rowg = block_row + wave * 16 + rr;
            const float xf = x[(size_t)rowg * 64 + 32 + cg];
            out[(size_t)rowg * 64 + 32 + cg] = spline_eval(sv, xf);
        }
    }
}

extern "C" void kernel_launch(void* const* d_in, const int* in_sizes, int n_in,
                              void* d_out, int out_size, void* d_ws, size_t ws_size,
                              hipStream_t stream) {
    const float* x = (const float*)d_in[0];
    const float* W = (const float*)d_in[1];
    const float* b = (const float*)d_in[2];
    float* out = (float*)d_out;

    if (d_ws != nullptr && ws_size >= 49152) {
        short* wsH = (short*)d_ws;
        short* wsL = wsH + 12288;
        prep_w<<<48, 256, 0, stream>>>(W, wsH, wsL);                     // 48 KB, L2-resident
        bern_spline_fast<<<2048, 256, 0, stream>>>(x, wsH, wsL, b, out); // 64 rows x 16 ch
    } else {
        bern_spline_fallback<<<1024, 256, 0, stream>>>(x, W, b, out);
    }
}

// Round 7
// 34.564 us; speedup vs baseline: 1.0883x; 1.0883x over previous
//
#include <hip/hip_runtime.h>

// BernsteinSplineCouplingBlock: BATCH=65536, CHANNELS=64, SPLIT1=SPLIT2=32, DEGREE=10
// out[:, :32] = x[:, :32]
// s = x1 @ W.T + b  -> [B*32, 12]; spline(s, x2) -> out[:, 32:]
// GEMM via split-bf16 (hi+lo) 3-MFMA chain for ~f32 precision.
// R7 = R6 with compile fix: __exp2f doesn't exist on HIP -> use exp2f().
//     B-frag prefetch, lane=(row,ch-pair) 8B vector IO, log2-domain cumsum.

typedef short v8s  __attribute__((ext_vector_type(8)));  // 8 x bf16 (4 VGPRs)
typedef float f32x4 __attribute__((ext_vector_type(4)));
typedef float f32x2 __attribute__((ext_vector_type(2)));

#define LOG2E 1.44269504088896340736f
#define LN2   0.69314718055994530942f

__device__ __forceinline__ short f2bf(float f) {
    union { float f; unsigned u; } v; v.f = f;
    return (short)((v.u + 0x7FFFu + ((v.u >> 16) & 1u)) >> 16);  // RNE
}

__device__ __forceinline__ float bf2f(short h) {
    union { unsigned u; float f; } v; v.u = ((unsigned)(unsigned short)h) << 16;
    return v.f;
}

__device__ __forceinline__ float sgn01(float x) {
    return (x > 0.f) ? 1.f : ((x < 0.f) ? -1.f : 0.f);
}

// log2-domain softplus: softplus(x)/ln2  (mul, v_exp, add, v_log)
__device__ __forceinline__ float softplus_l2(float x) {
    return __log2f(1.0f + exp2f(x * LOG2E));
}

// old-style eval (kept for fallback kernel, known-pass R3 math)
__device__ __forceinline__ float softplus_f(float x) {
    return __logf(1.0f + __expf(x));
}
__device__ __forceinline__ float spline_eval(const float* sv, float xf) {
    float cn[11];
    cn[0] = 0.f;
    float run = 0.f;
#pragma unroll
    for (int j = 0; j < 10; ++j) { run += softplus_f(sv[j]); cn[j + 1] = run; }
    const float inv = __fdividef(1.f, run);
    const float wd = softplus_f(sv[10]) + 0.1f;
    float hg = sv[11];
    hg += 0.1f * sgn01(hg);
    const float t   = __fdividef(xf, wd) + 0.5f;
    const float tc  = fminf(fmaxf(t, 0.f), 1.f);
#pragma unroll
    for (int n = 10; n >= 2; --n) {
#pragma unroll
        for (int i = 0; i < n; ++i) cn[i] += tc * (cn[i + 1] - cn[i]);
    }
    const float db    = cn[1] - cn[0];
    const float deriv = 10.f * db * inv;
    const float ym    = fmaf(tc, db, cn[0]) * inv;
    float y = (t < 0.f) ? (t * deriv)
            : ((t > 1.f) ? fmaf(t - 1.f, deriv, 1.f) : ym);
    return (y - 0.5f) * hg;
}

// ---- prep: split W f32 -> bf16 hi/lo in B-fragment order ----
// frag layout: [(k>>3)*3072 + out*8 + (k&7)], hi at wsH, lo at wsL
__global__ void prep_w(const float* __restrict__ W, short* __restrict__ wsH,
                       short* __restrict__ wsL) {
    const int g = blockIdx.x * 256 + threadIdx.x;
    if (g < 12288) {
        const int o = g >> 5;        // W row (out index 0..383)
        const int k = g & 31;
        const float w = W[g];
        const short hi = f2bf(w);
        const int off = (k >> 3) * 3072 + o * 8 + (k & 7);
        wsH[off] = hi;
        wsL[off] = f2bf(w - bf2f(hi));
    }
}

// ---- main: 2048 blocks = (row group) x (channel half), 4 waves, no barriers ----
__global__ __launch_bounds__(256) void bern_spline_fast(
    const float* __restrict__ x, const short* __restrict__ wsH,
    const short* __restrict__ wsL, const float* __restrict__ bias,
    float* __restrict__ out)
{
    __shared__ float sl[4 * 16 * 100];   // per-wave 16 rows x (96+4pad) f32, 25.6 KB

    const int tid  = threadIdx.x;
    const int wave = tid >> 6;
    const int lane = tid & 63;
    const int cbit = blockIdx.x & 1;            // channel half: ch in [cbit*16, +16)
    const int block_row = (blockIdx.x >> 1) * 64;

    const int row16 = lane & 15;
    const int kq    = lane >> 4;
    const int arow  = block_row + wave * 16 + row16;

    // A fragment: lane holds x1[row = l&15][k = (l>>4)*8 .. +7], hi+lo
    const f32x4 a0 = *(const f32x4*)(x + (size_t)arow * 64 + kq * 8);
    const f32x4 a1 = *(const f32x4*)(x + (size_t)arow * 64 + kq * 8 + 4);
    v8s ah, al;
#pragma unroll
    for (int e = 0; e < 4; ++e) {
        const short h0 = f2bf(a0[e]);
        ah[e] = h0;     al[e] = f2bf(a0[e] - bf2f(h0));
        const short h1 = f2bf(a1[e]);
        ah[e + 4] = h1; al[e + 4] = f2bf(a1[e] - bf2f(h1));
    }

    float* swv = sl + wave * 1600;   // wave-private transpose buffer
    const f32x4 zero4 = {0.f, 0.f, 0.f, 0.f};

    // ---- B-frag loads half 0 ----
    v8s bh0[6], bl0[6];
#pragma unroll
    for (int ot = 0; ot < 6; ++ot) {
        const int boff = kq * 3072 + ((cbit * 12 + ot) * 16 + row16) * 8;
        bh0[ot] = *(const v8s*)(wsH + boff);
        bl0[ot] = *(const v8s*)(wsL + boff);
    }

    // ---- MFMA half 0 + LDS scatter ----
#pragma unroll
    for (int ot = 0; ot < 6; ++ot) {
        f32x4 c = __builtin_amdgcn_mfma_f32_16x16x32_bf16(al, bh0[ot], zero4, 0, 0, 0);
        c = __builtin_amdgcn_mfma_f32_16x16x32_bf16(ah, bl0[ot], c, 0, 0, 0);
        c = __builtin_amdgcn_mfma_f32_16x16x32_bf16(ah, bh0[ot], c, 0, 0, 0);
#pragma unroll
        for (int r = 0; r < 4; ++r)
            swv[(kq * 4 + r) * 100 + ot * 16 + row16] = c[r];
    }

    // ---- PREFETCH: B-frag loads half 1 (in flight during half-0 splines) ----
    v8s bh1[6], bl1[6];
#pragma unroll
    for (int ot = 0; ot < 6; ++ot) {
        const int boff = kq * 3072 + ((cbit * 12 + 6 + ot) * 16 + row16) * 8;
        bh1[ot] = *(const v8s*)(wsH + boff);
        bl1[ot] = *(const v8s*)(wsL + boff);
    }

    // ---- splines: lane = (row16, channel pair 2*kq, 2*kq+1) per half ----
#pragma unroll
    for (int hf = 0; hf < 2; ++hf) {
        if (hf == 1) {
            // MFMA half 1 + LDS scatter (prefetched B-frags)
#pragma unroll
            for (int ot = 0; ot < 6; ++ot) {
                f32x4 c = __builtin_amdgcn_mfma_f32_16x16x32_bf16(al, bh1[ot], zero4, 0, 0, 0);
                c = __builtin_amdgcn_mfma_f32_16x16x32_bf16(ah, bl1[ot], c, 0, 0, 0);
                c = __builtin_amdgcn_mfma_f32_16x16x32_bf16(ah, bh1[ot], c, 0, 0, 0);
#pragma unroll
                for (int r = 0; r < 4; ++r)
                    swv[(kq * 4 + r) * 100 + ot * 16 + row16] = c[r];
            }
        }

        const int cg0 = cbit * 16 + hf * 8 + 2 * kq;   // global channel of spline A
        // xf pair (8B) — issued early, consumed mid-spline
        const f32x2 xf2 = *(const f32x2*)(x + (size_t)arow * 64 + 32 + cg0);

        // s-values: 24 consecutive floats in swv row; bias: 24 consecutive floats
        const float* sp = swv + row16 * 100 + 2 * kq * 12;
        const f32x4 sA0 = *(const f32x4*)(sp);
        const f32x4 sA1 = *(const f32x4*)(sp + 4);
        const f32x4 sA2 = *(const f32x4*)(sp + 8);
        const f32x4 sB0 = *(const f32x4*)(sp + 12);
        const f32x4 sB1 = *(const f32x4*)(sp + 16);
        const f32x4 sB2 = *(const f32x4*)(sp + 20);
        const float* bp = bias + cg0 * 12;
        const f32x4 bA0 = *(const f32x4*)(bp);
        const f32x4 bA1 = *(const f32x4*)(bp + 4);
        const f32x4 bA2 = *(const f32x4*)(bp + 8);
        const f32x4 bB0 = *(const f32x4*)(bp + 12);
        const f32x4 bB1 = *(const f32x4*)(bp + 16);
        const f32x4 bB2 = *(const f32x4*)(bp + 20);

        float svA[12], svB[12];
#pragma unroll
        for (int e = 0; e < 4; ++e) {
            svA[e]     = sA0[e] + bA0[e];
            svA[e + 4] = sA1[e] + bA1[e];
            svA[e + 8] = sA2[e] + bA2[e];
            svB[e]     = sB0[e] + bB0[e];
            svB[e + 4] = sB1[e] + bB1[e];
            svB[e + 8] = sB2[e] + bB2[e];
        }

        // interleaved pair: cumsum(softplus) in log2 units (ln2 cancels after norm)
        float cnA[11], cnB[11];
        cnA[0] = 0.f; cnB[0] = 0.f;
        float runA = 0.f, runB = 0.f;
#pragma unroll
        for (int j = 0; j < 10; ++j) {
            runA += softplus_l2(svA[j]); cnA[j + 1] = runA;
            runB += softplus_l2(svB[j]); cnB[j + 1] = runB;
        }
        const float invA = __fdividef(1.f, runA);
        const float invB = __fdividef(1.f, runB);

        const float wdA = fmaf(LN2, softplus_l2(svA[10]), 0.1f);  // softplus>0 => +0.1
        const float wdB = fmaf(LN2, softplus_l2(svB[10]), 0.1f);
        float hgA = svA[11]; hgA += 0.1f * sgn01(hgA);
        float hgB = svB[11]; hgB += 0.1f * sgn01(hgB);

        const float tA  = __fdividef(xf2[0], wdA) + 0.5f;
        const float tB  = __fdividef(xf2[1], wdB) + 0.5f;
        const float tcA = fminf(fmaxf(tA, 0.f), 1.f);
        const float tcB = fminf(fmaxf(tB, 0.f), 1.f);

        // de Casteljau to degree 1 (9 steps), two chains interleaved for ILP
#pragma unroll
        for (int n = 10; n >= 2; --n) {
#pragma unroll
            for (int i = 0; i < n; ++i) {
                cnA[i] += tcA * (cnA[i + 1] - cnA[i]);
                cnB[i] += tcB * (cnB[i + 1] - cnB[i]);
            }
        }
        const float dbA = cnA[1] - cnA[0];
        const float dbB = cnB[1] - cnB[0];
        const float derA = 10.f * dbA * invA;
        const float derB = 10.f * dbB * invB;
        const float ymA = fmaf(tcA, dbA, cnA[0]) * invA;
        const float ymB = fmaf(tcB, dbB, cnB[0]) * invB;

        float yA = (tA < 0.f) ? (tA * derA)
                 : ((tA > 1.f) ? fmaf(tA - 1.f, derA, 1.f) : ymA);
        float yB = (tB < 0.f) ? (tB * derB)
                 : ((tB > 1.f) ? fmaf(tB - 1.f, derB, 1.f) : ymB);

        f32x2 y2;
        y2[0] = (yA - 0.5f) * hgA;
        y2[1] = (yB - 0.5f) * hgB;
        *(f32x2*)(out + (size_t)arow * 64 + 32 + cg0) = y2;
    }

    // ---- x1 passthrough at end: only even blocks (one copy per row group) ----
    if (cbit == 0) {
        for (int i = tid; i < 512; i += 256) {
            const int r = i >> 3, q = i & 7;               // 64 rows x 8 quads
            *(f32x4*)(out + (size_t)(block_row + r) * 64 + q * 4) =
                *(const f32x4*)(x + (size_t)(block_row + r) * 64 + q * 4);
        }
    }
}

// ---- fallback (R3 structure, known-pass): used only if ws is too small ----
__global__ __launch_bounds__(256) void bern_spline_fallback(
    const float* __restrict__ x, const float* __restrict__ W,
    const float* __restrict__ bias, float* __restrict__ out)
{
    __shared__ short Wh[12288];
    __shared__ short Wl[12288];
    __shared__ float bl[384];
    __shared__ float sl[4 * 16 * 100];

    const int tid  = threadIdx.x;
    const int wave = tid >> 6;
    const int lane = tid & 63;
    const int block_row = blockIdx.x * 64;

    for (int g = tid; g < 12288; g += 256) {
        const int o = g >> 5;
        const int k = g & 31;
        const float w = W[g];
        const short hi = f2bf(w);
        Wh[(k >> 3) * 3072 + o * 8 + (k & 7)] = hi;
        Wl[(k >> 3) * 3072 + o * 8 + (k & 7)] = f2bf(w - bf2f(hi));
    }
    for (int g = tid; g < 384; g += 256) bl[g] = bias[g];
    __syncthreads();

    for (int i = tid; i < 512; i += 256) {
        const int r = i >> 3, q = i & 7;
        *(f32x4*)(out + (size_t)(block_row + r) * 64 + q * 4) =
            *(const f32x4*)(x + (size_t)(block_row + r) * 64 + q * 4);
    }

    const int row16 = lane & 15;
    const int kq    = lane >> 4;
    const int arow  = block_row + wave * 16 + row16;
    const f32x4 a0 = *(const f32x4*)(x + (size_t)arow * 64 + kq * 8);
    const f32x4 a1 = *(const f32x4*)(x + (size_t)arow * 64 + kq * 8 + 4);
    v8s ah, al;
#pragma unroll
    for (int e = 0; e < 4; ++e) {
        const short h0 = f2bf(a0[e]);
        ah[e] = h0;     al[e] = f2bf(a0[e] - bf2f(h0));
        const short h1 = f2bf(a1[e]);
        ah[e + 4] = h1; al[e + 4] = f2bf(a1[e] - bf2f(h1));
    }

    float* swv = sl + wave * 1600;
    const f32x4 zero4 = {0.f, 0.f, 0.f, 0.f};

    for (int qt = 0; qt < 4; ++qt) {
        f32x4 acc[6];
#pragma unroll
        for (int ot = 0; ot < 6; ++ot) {
            const int otg = qt * 6 + ot;
            const int boff = kq * 3072 + (otg * 16 + row16) * 8;
            const v8s bh  = *(const v8s*)(Wh + boff);
            const v8s blo = *(const v8s*)(Wl + boff);
            f32x4 c = __builtin_amdgcn_mfma_f32_16x16x32_bf16(al, bh, zero4, 0, 0, 0);
            c = __builtin_amdgcn_mfma_f32_16x16x32_bf16(ah, blo, c, 0, 0, 0);
            acc[ot] = __builtin_amdgcn_mfma_f32_16x16x32_bf16(ah, bh, c, 0, 0, 0);
        }
#pragma unroll
        for (int ot = 0; ot < 6; ++ot)
#pragma unroll
            for (int r = 0; r < 4; ++r)
                swv[(kq * 4 + r) * 100 + ot * 16 + row16] = acc[ot][r];

#pragma unroll
        for (int p = 0; p < 2; ++p) {
            const int idx = p * 64 + lane;
            const int cl  = idx & 7;
            const int rr  = idx >> 3;
            const int cg  = qt * 8 + cl;

            const float* sp = swv + rr * 100 + cl * 12;
            const f32x4 s0 = *(const f32x4*)(sp);
            const f32x4 s1 = *(const f32x4*)(sp + 4);
            const f32x4 s2 = *(const f32x4*)(sp + 8);
            const f32x4 b0 = *(const f32x4*)(bl + cg * 12);
            const f32x4 b1 = *(const f32x4*)(bl + cg * 12 + 4);
            const f32x4 b2 = *(const f32x4*)(bl + cg * 12 + 8);

            float sv[12];
            sv[0]  = s0[0] + b0[0]; sv[1]  = s0[1] + b0[1];
            sv[2]  = s0[2] + b0[2]; sv[3]  = s0[3] + b0[3];
            sv[4]  = s1[0] + b1[0]; sv[5]  = s1[1] + b1[1];
            sv[6]  = s1[2] + b1[2]; sv[7]  = s1[3] + b1[3];
            sv[8]  = s2[0] + b2[0]; sv[9]  = s2[1] + b2[1];
            sv[10] = s2[2] + b2[2]; sv[11] = s2[3] + b2[3];

            const int rowg = block_row + wave * 16 + rr;
            const float xf = x[(size_t)rowg * 64 + 32 + cg];
            out[(size_t)rowg * 64 + 32 + cg] = spline_eval(sv, xf);
        }
    }
}

extern "C" void kernel_launch(void* const* d_in, const int* in_sizes, int n_in,
                              void* d_out, int out_size, void* d_ws, size_t ws_size,
                              hipStream_t stream) {
    const float* x = (const float*)d_in[0];
    const float* W = (const float*)d_in[1];
    const float* b = (const float*)d_in[2];
    float* out = (float*)d_out;

    if (d_ws != nullptr && ws_size >= 49152) {
        short* wsH = (short*)d_ws;
        short* wsL = wsH + 12288;
        prep_w<<<48, 256, 0, stream>>>(W, wsH, wsL);                     // 48 KB, L2-resident
        bern_spline_fast<<<2048, 256, 0, stream>>>(x, wsH, wsL, b, out); // 64 rows x 16 ch
    } else {
        bern_spline_fallback<<<1024, 256, 0, stream>>>(x, W, b, out);
    }
}

// Round 8
// 32.206 us; speedup vs baseline: 1.1679x; 1.0732x over previous
//
#include <hip/hip_runtime.h>

// BernsteinSplineCouplingBlock: BATCH=65536, CHANNELS=64, SPLIT1=SPLIT2=32, DEGREE=10
// out[:, :32] = x[:, :32]
// s = x1 @ W.T + b  -> [B*32, 12]; spline(s, x2) -> out[:, 32:]
// GEMM via split-bf16 (hi+lo) 3-MFMA chain for ~f32 precision.
// R8: bias folded into MFMA C-in; Horner-Bernstein (value+deriv, shared t-powers)
//     replaces de Casteljau; deriv coeffs = raw softplus outputs (cumsum diff).

typedef short v8s  __attribute__((ext_vector_type(8)));  // 8 x bf16 (4 VGPRs)
typedef float f32x4 __attribute__((ext_vector_type(4)));
typedef float f32x2 __attribute__((ext_vector_type(2)));

#define LOG2E 1.44269504088896340736f
#define LN2   0.69314718055994530942f

__device__ __forceinline__ short f2bf(float f) {
    union { float f; unsigned u; } v; v.f = f;
    return (short)((v.u + 0x7FFFu + ((v.u >> 16) & 1u)) >> 16);  // RNE
}

__device__ __forceinline__ float bf2f(short h) {
    union { unsigned u; float f; } v; v.u = ((unsigned)(unsigned short)h) << 16;
    return v.f;
}

__device__ __forceinline__ float sgn01(float x) {
    return (x > 0.f) ? 1.f : ((x < 0.f) ? -1.f : 0.f);
}

// log2-domain softplus: softplus(x)/ln2  (mul, v_exp, add, v_log)
__device__ __forceinline__ float softplus_l2(float x) {
    return __log2f(1.0f + exp2f(x * LOG2E));
}

// R8 spline: Horner-Bernstein. sv[0..9] raw coeffs, sv[10] width, sv[11] height.
__device__ __forceinline__ float spline_horner(const float* sv, float xf) {
    // cumsum(softplus) in log2 units; ln2 cancels under inv-normalization.
    float spv[10], cn_[11];
    cn_[0] = 0.f;
    float run = 0.f;
#pragma unroll
    for (int j = 0; j < 10; ++j) {
        spv[j] = softplus_l2(sv[j]);
        run += spv[j];
        cn_[j + 1] = run;
    }
    const float inv = __fdividef(1.f, run);

    const float wd = fmaf(LN2, softplus_l2(sv[10]), 0.1f);  // softplus>0 => +0.1
    float hg = sv[11];
    hg += 0.1f * sgn01(hg);

    const float t  = __fdividef(xf, wd) + 0.5f;
    const float tc = fminf(fmaxf(t, 0.f), 1.f);
    const float s  = 1.f - tc;

    // P = sum_{i=1..10} C10_i cn_[i] tc^i s^(10-i)   (value, unnormalized)
    // Q = sum_{i=0..9}  C9_i  spv[i] tc^i s^(9-i)    (deriv/10, unnormalized)
    // ascending recurrence: X = fma(X, s, tk*w_i), tk *= tc  (chains independent)
    const float C10[11] = {1.f,10.f,45.f,120.f,210.f,252.f,210.f,120.f,45.f,10.f,1.f};
    const float C9[10]  = {1.f,9.f,36.f,84.f,126.f,126.f,84.f,36.f,9.f,1.f};
    float tk = 1.f, P = 0.f, Q = 0.f;
#pragma unroll
    for (int i = 0; i < 10; ++i) {
        Q = fmaf(Q, s, tk * (C9[i] * spv[i]));
        P = fmaf(P, s, tk * (C10[i] * cn_[i]));   // i=0 term folds to 0
        tk *= tc;
    }
    P = fmaf(P, s, tk * cn_[10]);                 // i=10, C(10,10)=1

    const float der = 10.f * Q * inv;
    const float ym  = P * inv;
    float y = (t < 0.f) ? (t * der)
            : ((t > 1.f) ? fmaf(t - 1.f, der, 1.f) : ym);
    return (y - 0.5f) * hg;
}

// fallback math (R3-proven de Casteljau)
__device__ __forceinline__ float softplus_f(float x) {
    return __logf(1.0f + __expf(x));
}
__device__ __forceinline__ float spline_eval(const float* sv, float xf) {
    float cn[11];
    cn[0] = 0.f;
    float run = 0.f;
#pragma unroll
    for (int j = 0; j < 10; ++j) { run += softplus_f(sv[j]); cn[j + 1] = run; }
    const float inv = __fdividef(1.f, run);
    const float wd = softplus_f(sv[10]) + 0.1f;
    float hg = sv[11];
    hg += 0.1f * sgn01(hg);
    const float t   = __fdividef(xf, wd) + 0.5f;
    const float tc  = fminf(fmaxf(t, 0.f), 1.f);
#pragma unroll
    for (int n = 10; n >= 2; --n) {
#pragma unroll
        for (int i = 0; i < n; ++i) cn[i] += tc * (cn[i + 1] - cn[i]);
    }
    const float db    = cn[1] - cn[0];
    const float deriv = 10.f * db * inv;
    const float ym    = fmaf(tc, db, cn[0]) * inv;
    float y = (t < 0.f) ? (t * deriv)
            : ((t > 1.f) ? fmaf(t - 1.f, deriv, 1.f) : ym);
    return (y - 0.5f) * hg;
}

// ---- prep: split W f32 -> bf16 hi/lo in B-fragment order ----
// frag layout: [(k>>3)*3072 + out*8 + (k&7)], hi at wsH, lo at wsL
__global__ void prep_w(const float* __restrict__ W, short* __restrict__ wsH,
                       short* __restrict__ wsL) {
    const int g = blockIdx.x * 256 + threadIdx.x;
    if (g < 12288) {
        const int o = g >> 5;        // W row (out index 0..383)
        const int k = g & 31;
        const float w = W[g];
        const short hi = f2bf(w);
        const int off = (k >> 3) * 3072 + o * 8 + (k & 7);
        wsH[off] = hi;
        wsL[off] = f2bf(w - bf2f(hi));
    }
}

// ---- main: 2048 blocks = (row group) x (channel half), 4 waves, no barriers ----
__global__ __launch_bounds__(256) void bern_spline_fast(
    const float* __restrict__ x, const short* __restrict__ wsH,
    const short* __restrict__ wsL, const float* __restrict__ bias,
    float* __restrict__ out)
{
    __shared__ float sl[4 * 16 * 100];   // per-wave 16 rows x (96+4pad) f32, 25.6 KB

    const int tid  = threadIdx.x;
    const int wave = tid >> 6;
    const int lane = tid & 63;
    const int cbit = blockIdx.x & 1;            // channel half: ch in [cbit*16, +16)
    const int block_row = (blockIdx.x >> 1) * 64;

    const int row16 = lane & 15;
    const int kq    = lane >> 4;
    const int arow  = block_row + wave * 16 + row16;

    // xf pairs for both halves — issued first, consumed deep in spline phase
    const int cg0_h0 = cbit * 16 + 2 * kq;
    const f32x2 xf2_0 = *(const f32x2*)(x + (size_t)arow * 64 + 32 + cg0_h0);
    const f32x2 xf2_1 = *(const f32x2*)(x + (size_t)arow * 64 + 32 + cg0_h0 + 8);

    // A fragment: lane holds x1[row = l&15][k = (l>>4)*8 .. +7], hi+lo
    const f32x4 a0 = *(const f32x4*)(x + (size_t)arow * 64 + kq * 8);
    const f32x4 a1 = *(const f32x4*)(x + (size_t)arow * 64 + kq * 8 + 4);
    v8s ah, al;
#pragma unroll
    for (int e = 0; e < 4; ++e) {
        const short h0 = f2bf(a0[e]);
        ah[e] = h0;     al[e] = f2bf(a0[e] - bf2f(h0));
        const short h1 = f2bf(a1[e]);
        ah[e + 4] = h1; al[e + 4] = f2bf(a1[e] - bf2f(h1));
    }

    // bias per C tile: constant along batch-row dim -> MFMA C-in {bv,bv,bv,bv}
    float bv0[6], bv1[6];
#pragma unroll
    for (int ot = 0; ot < 6; ++ot) {
        bv0[ot] = bias[(cbit * 12 + ot) * 16 + row16];
        bv1[ot] = bias[(cbit * 12 + 6 + ot) * 16 + row16];
    }

    float* swv = sl + wave * 1600;   // wave-private transpose buffer

    // ---- B-frag loads half 0 ----
    v8s bh0[6], bl0[6];
#pragma unroll
    for (int ot = 0; ot < 6; ++ot) {
        const int boff = kq * 3072 + ((cbit * 12 + ot) * 16 + row16) * 8;
        bh0[ot] = *(const v8s*)(wsH + boff);
        bl0[ot] = *(const v8s*)(wsL + boff);
    }

    // ---- MFMA half 0 (bias in C) + LDS scatter ----
#pragma unroll
    for (int ot = 0; ot < 6; ++ot) {
        f32x4 cb; cb[0] = bv0[ot]; cb[1] = bv0[ot]; cb[2] = bv0[ot]; cb[3] = bv0[ot];
        f32x4 c = __builtin_amdgcn_mfma_f32_16x16x32_bf16(al, bh0[ot], cb, 0, 0, 0);
        c = __builtin_amdgcn_mfma_f32_16x16x32_bf16(ah, bl0[ot], c, 0, 0, 0);
        c = __builtin_amdgcn_mfma_f32_16x16x32_bf16(ah, bh0[ot], c, 0, 0, 0);
#pragma unroll
        for (int r = 0; r < 4; ++r)
            swv[(kq * 4 + r) * 100 + ot * 16 + row16] = c[r];
    }

    // ---- PREFETCH: B-frag loads half 1 (in flight during half-0 splines) ----
    v8s bh1[6], bl1[6];
#pragma unroll
    for (int ot = 0; ot < 6; ++ot) {
        const int boff = kq * 3072 + ((cbit * 12 + 6 + ot) * 16 + row16) * 8;
        bh1[ot] = *(const v8s*)(wsH + boff);
        bl1[ot] = *(const v8s*)(wsL + boff);
    }

    // ---- splines: lane = (row16, channel pair 2*kq, 2*kq+1) per half ----
#pragma unroll
    for (int hf = 0; hf < 2; ++hf) {
        if (hf == 1) {
            // MFMA half 1 (bias in C) + LDS scatter (prefetched B-frags)
#pragma unroll
            for (int ot = 0; ot < 6; ++ot) {
                f32x4 cb; cb[0] = bv1[ot]; cb[1] = bv1[ot]; cb[2] = bv1[ot]; cb[3] = bv1[ot];
                f32x4 c = __builtin_amdgcn_mfma_f32_16x16x32_bf16(al, bh1[ot], cb, 0, 0, 0);
                c = __builtin_amdgcn_mfma_f32_16x16x32_bf16(ah, bl1[ot], c, 0, 0, 0);
                c = __builtin_amdgcn_mfma_f32_16x16x32_bf16(ah, bh1[ot], c, 0, 0, 0);
#pragma unroll
                for (int r = 0; r < 4; ++r)
                    swv[(kq * 4 + r) * 100 + ot * 16 + row16] = c[r];
            }
        }

        const int cg0 = cbit * 16 + hf * 8 + 2 * kq;   // global channel of spline A
        const f32x2 xf2 = (hf == 0) ? xf2_0 : xf2_1;

        // s-values (bias already in): 24 consecutive floats in swv row
        const float* sp = swv + row16 * 100 + 2 * kq * 12;
        float svA[12], svB[12];
#pragma unroll
        for (int e = 0; e < 4; ++e) {
            const f32x4 vA0 = *(const f32x4*)(sp);
            const f32x4 vA1 = *(const f32x4*)(sp + 4);
            const f32x4 vA2 = *(const f32x4*)(sp + 8);
            const f32x4 vB0 = *(const f32x4*)(sp + 12);
            const f32x4 vB1 = *(const f32x4*)(sp + 16);
            const f32x4 vB2 = *(const f32x4*)(sp + 20);
            svA[e]     = vA0[e];
            svA[e + 4] = vA1[e];
            svA[e + 8] = vA2[e];
            svB[e]     = vB0[e];
            svB[e + 4] = vB1[e];
            svB[e + 8] = vB2[e];
        }

        f32x2 y2;
        y2[0] = spline_horner(svA, xf2[0]);
        y2[1] = spline_horner(svB, xf2[1]);
        *(f32x2*)(out + (size_t)arow * 64 + 32 + cg0) = y2;
    }

    // ---- x1 passthrough at end: only even blocks (one copy per row group) ----
    if (cbit == 0) {
        for (int i = tid; i < 512; i += 256) {
            const int r = i >> 3, q = i & 7;               // 64 rows x 8 quads
            *(f32x4*)(out + (size_t)(block_row + r) * 64 + q * 4) =
                *(const f32x4*)(x + (size_t)(block_row + r) * 64 + q * 4);
        }
    }
}

// ---- fallback (R3 structure, known-pass): used only if ws is too small ----
__global__ __launch_bounds__(256) void bern_spline_fallback(
    const float* __restrict__ x, const float* __restrict__ W,
    const float* __restrict__ bias, float* __restrict__ out)
{
    __shared__ short Wh[12288];
    __shared__ short Wl[12288];
    __shared__ float bl[384];
    __shared__ float sl[4 * 16 * 100];

    const int tid  = threadIdx.x;
    const int wave = tid >> 6;
    const int lane = tid & 63;
    const int block_row = blockIdx.x * 64;

    for (int g = tid; g < 12288; g += 256) {
        const int o = g >> 5;
        const int k = g & 31;
        const float w = W[g];
        const short hi = f2bf(w);
        Wh[(k >> 3) * 3072 + o * 8 + (k & 7)] = hi;
        Wl[(k >> 3) * 3072 + o * 8 + (k & 7)] = f2bf(w - bf2f(hi));
    }
    for (int g = tid; g < 384; g += 256) bl[g] = bias[g];
    __syncthreads();

    for (int i = tid; i < 512; i += 256) {
        const int r = i >> 3, q = i & 7;
        *(f32x4*)(out + (size_t)(block_row + r) * 64 + q * 4) =
            *(const f32x4*)(x + (size_t)(block_row + r) * 64 + q * 4);
    }

    const int row16 = lane & 15;
    const int kq    = lane >> 4;
    const int arow  = block_row + wave * 16 + row16;
    const f32x4 a0 = *(const f32x4*)(x + (size_t)arow * 64 + kq * 8);
    const f32x4 a1 = *(const f32x4*)(x + (size_t)arow * 64 + kq * 8 + 4);
    v8s ah, al;
#pragma unroll
    for (int e = 0; e < 4; ++e) {
        const short h0 = f2bf(a0[e]);
        ah[e] = h0;     al[e] = f2bf(a0[e] - bf2f(h0));
        const short h1 = f2bf(a1[e]);
        ah[e + 4] = h1; al[e + 4] = f2bf(a1[e] - bf2f(h1));
    }

    float* swv = sl + wave * 1600;
    const f32x4 zero4 = {0.f, 0.f, 0.f, 0.f};

    for (int qt = 0; qt < 4; ++qt) {
        f32x4 acc[6];
#pragma unroll
        for (int ot = 0; ot < 6; ++ot) {
            const int otg = qt * 6 + ot;
            const int boff = kq * 3072 + (otg * 16 + row16) * 8;
            const v8s bh  = *(const v8s*)(Wh + boff);
            const v8s blo = *(const v8s*)(Wl + boff);
            f32x4 c = __builtin_amdgcn_mfma_f32_16x16x32_bf16(al, bh, zero4, 0, 0, 0);
            c = __builtin_amdgcn_mfma_f32_16x16x32_bf16(ah, blo, c, 0, 0, 0);
            acc[ot] = __builtin_amdgcn_mfma_f32_16x16x32_bf16(ah, bh, c, 0, 0, 0);
        }
#pragma unroll
        for (int ot = 0; ot < 6; ++ot)
#pragma unroll
            for (int r = 0; r < 4; ++r)
                swv[(kq * 4 + r) * 100 + ot * 16 + row16] = acc[ot][r];

#pragma unroll
        for (int p = 0; p < 2; ++p) {
            const int idx = p * 64 + lane;
            const int cl  = idx & 7;
            const int rr  = idx >> 3;
            const int cg  = qt * 8 + cl;

            const float* sp = swv + rr * 100 + cl * 12;
            const f32x4 s0 = *(const f32x4*)(sp);
            const f32x4 s1 = *(const f32x4*)(sp + 4);
            const f32x4 s2 = *(const f32x4*)(sp + 8);
            const f32x4 b0 = *(const f32x4*)(bl + cg * 12);
            const f32x4 b1 = *(const f32x4*)(bl + cg * 12 + 4);
            const f32x4 b2 = *(const f32x4*)(bl + cg * 12 + 8);

            float sv[12];
            sv[0]  = s0[0] + b0[0]; sv[1]  = s0[1] + b0[1];
            sv[2]  = s0[2] + b0[2]; sv[3]  = s0[3] + b0[3];
            sv[4]  = s1[0] + b1[0]; sv[5]  = s1[1] + b1[1];
            sv[6]  = s1[2] + b1[2]; sv[7]  = s1[3] + b1[3];
            sv[8]  = s2[0] + b2[0]; sv[9]  = s2[1] + b2[1];
            sv[10] = s2[2] + b2[2]; sv[11] = s2[3] + b2[3];

            const int rowg = block_row + wave * 16 + rr;
            const float xf = x[(size_t)rowg * 64 + 32 + cg];
            out[(size_t)rowg * 64 + 32 + cg] = spline_eval(sv, xf);
        }
    }
}

extern "C" void kernel_launch(void* const* d_in, const int* in_sizes, int n_in,
                              void* d_out, int out_size, void* d_ws, size_t ws_size,
                              hipStream_t stream) {
    const float* x = (const float*)d_in[0];
    const float* W = (const float*)d_in[1];
    const float* b = (const float*)d_in[2];
    float* out = (float*)d_out;

    if (d_ws != nullptr && ws_size >= 49152) {
        short* wsH = (short*)d_ws;
        short* wsL = wsH + 12288;
        prep_w<<<48, 256, 0, stream>>>(W, wsH, wsL);                     // 48 KB, L2-resident
        bern_spline_fast<<<2048, 256, 0, stream>>>(x, wsH, wsL, b, out); // 64 rows x 16 ch
    } else {
        bern_spline_fallback<<<1024, 256, 0, stream>>>(x, W, b, out);
    }
}